// Round 2
// baseline (547.867 us; speedup 1.0000x reference)
//
#include <hip/hip_runtime.h>

// RGCN vulnerability classifier, fp32, MI355X.
// degrees -> rsqrt -> [proj(+out-norm) -> edge scatter(+in-norm)] x2 -> mean pool -> 32x2 classifier.
// Workspace-adaptive: tier1 (ws>=44.8MB) batches relations; tier3 (ws>=26.5MB) chunks nodes.

#define N_NODES 100000
#define N_REL   8
#define N_EDGES 80000
#define IN_F    128
#define HID     32
#define N_GRAPHS 64

constexpr int TILE = 256;  // nodes per projection block
constexpr int KC   = 32;   // k-chunk staged in LDS

__global__ __launch_bounds__(256) void deg_kernel(const int* __restrict__ src, const int* __restrict__ dst,
                                                  int* __restrict__ dego, int* __restrict__ degi, int n_rel) {
  int i = blockIdx.x * 256 + threadIdx.x;
  if (i < n_rel * N_EDGES) {
    int r = i / N_EDGES;
    atomicAdd(&dego[r * N_NODES + src[i]], 1);
    atomicAdd(&degi[r * N_NODES + dst[i]], 1);
  }
}

// in-place: int degree -> rsqrt(max(deg,1))
__global__ __launch_bounds__(256) void rsqrt_kernel(float* __restrict__ p, int count) {
  int i = blockIdx.x * 256 + threadIdx.x;
  if (i < count) {
    int d = ((const int*)p)[i];
    p[i] = rsqrtf((float)(d < 1 ? 1 : d));
  }
}

// Layer-1 projection for nodes [n0,n1): hw[rr][n-n0][j] = (x[n]*rs_o[rr][n]) @ W1[r0+rr]
// thread = node; x tile in LDS (stride 36 -> conflict-free b128); W wave-uniform -> scalar loads.
__global__ __launch_bounds__(256) void proj1_kernel(const float* __restrict__ x, const float* __restrict__ W1r0,
                                                    const float* __restrict__ rs_o, float* __restrict__ hw,
                                                    int n0, int n1, int hw_nodes) {
  int rr = blockIdx.y;
  int nb = n0 + blockIdx.x * TILE;
  int t = threadIdx.x;
  __shared__ float xs[TILE][KC + 4];
  const float* __restrict__ Wr = W1r0 + (size_t)rr * (IN_F * HID);
  float acc[HID];
#pragma unroll
  for (int j = 0; j < HID; j++) acc[j] = 0.f;

  for (int kc = 0; kc < IN_F; kc += KC) {
    __syncthreads();
#pragma unroll
    for (int i = 0; i < (TILE * KC / 4) / 256; i++) {  // 8 float4 per thread
      int q = t + i * 256;
      int nn = q >> 3, k4 = q & 7;
      int n = nb + nn;
      float4 v = make_float4(0.f, 0.f, 0.f, 0.f);
      if (n < n1) v = *(const float4*)&x[(size_t)n * IN_F + kc + k4 * 4];
      *(float4*)&xs[nn][k4 * 4] = v;
    }
    __syncthreads();
#pragma unroll
    for (int k4 = 0; k4 < KC / 4; k4++) {
      float4 xv = *(const float4*)&xs[t][k4 * 4];
      const float* wk = &Wr[(kc + k4 * 4) * HID];
#pragma unroll
      for (int j = 0; j < HID; j++) acc[j] += xv.x * wk[j];
#pragma unroll
      for (int j = 0; j < HID; j++) acc[j] += xv.y * wk[HID + j];
#pragma unroll
      for (int j = 0; j < HID; j++) acc[j] += xv.z * wk[2 * HID + j];
#pragma unroll
      for (int j = 0; j < HID; j++) acc[j] += xv.w * wk[3 * HID + j];
    }
  }
  int n = nb + t;
  if (n < n1) {
    float s = rs_o[(size_t)rr * N_NODES + n];
    float* o = &hw[((size_t)rr * hw_nodes + (n - n0)) * HID];
#pragma unroll
    for (int j4 = 0; j4 < HID / 4; j4++) {
      float4 v = make_float4(acc[j4 * 4] * s, acc[j4 * 4 + 1] * s, acc[j4 * 4 + 2] * s, acc[j4 * 4 + 3] * s);
      *(float4*)&o[j4 * 4] = v;
    }
  }
}

// Edge scatter: acc[d][j] += hw[rr][s-n0][j] * rs_i[rr][d] for src in [n0,n1). 32 lanes/edge.
__global__ __launch_bounds__(256) void scatter_kernel(const float* __restrict__ hw, const int* __restrict__ src,
                                                      const int* __restrict__ dst, const float* __restrict__ rs_i,
                                                      float* __restrict__ acc, int nr, int n0, int n1, int hw_nodes) {
  long i = (long)blockIdx.x * 256 + threadIdx.x;
  long total = (long)nr * N_EDGES * HID;
  if (i >= total) return;
  int j = (int)(i & (HID - 1));
  long e = i >> 5;
  int rr = (int)(e / N_EDGES);
  int ee = (int)(e - (long)rr * N_EDGES);
  int s = src[rr * N_EDGES + ee];
  if (s < n0 || s >= n1) return;
  int d = dst[rr * N_EDGES + ee];
  float v = hw[((size_t)rr * hw_nodes + (s - n0)) * HID + j] * rs_i[(size_t)rr * N_NODES + d];
  atomicAdd(&acc[(size_t)d * HID + j], v);
}

// Layer-2 projection fused with bias+relu of layer-1 accumulator.
__global__ __launch_bounds__(256) void proj2_kernel(const float* __restrict__ acc1, const float* __restrict__ b1,
                                                    const float* __restrict__ W2r0, const float* __restrict__ rs_o,
                                                    float* __restrict__ hw, int n0, int n1, int hw_nodes) {
  int n = n0 + blockIdx.x * 256 + threadIdx.x;
  if (n >= n1) return;
  int rr = blockIdx.y;
  float h1[HID];
#pragma unroll
  for (int j4 = 0; j4 < HID / 4; j4++) {
    float4 v = *(const float4*)&acc1[(size_t)n * HID + j4 * 4];
    h1[j4 * 4 + 0] = v.x; h1[j4 * 4 + 1] = v.y; h1[j4 * 4 + 2] = v.z; h1[j4 * 4 + 3] = v.w;
  }
#pragma unroll
  for (int j = 0; j < HID; j++) {
    float sb = 0.f;
#pragma unroll
    for (int q = 0; q < N_REL; q++) sb += b1[q * HID + j];
    h1[j] = fmaxf(h1[j] + sb, 0.f);
  }
  const float* __restrict__ Wr = W2r0 + (size_t)rr * (HID * HID);
  float acc[HID];
#pragma unroll
  for (int j = 0; j < HID; j++) acc[j] = 0.f;
#pragma unroll
  for (int k = 0; k < HID; k++) {
    float hv = h1[k];
#pragma unroll
    for (int j = 0; j < HID; j++) acc[j] += hv * Wr[k * HID + j];
  }
  float s = rs_o[(size_t)rr * N_NODES + n];
  float* o = &hw[((size_t)rr * hw_nodes + (n - n0)) * HID];
#pragma unroll
  for (int j4 = 0; j4 < HID / 4; j4++) {
    float4 v = make_float4(acc[j4 * 4] * s, acc[j4 * 4 + 1] * s, acc[j4 * 4 + 2] * s, acc[j4 * 4 + 3] * s);
    *(float4*)&o[j4 * 4] = v;
  }
}

// Per-graph sum pool with LDS staging; lane = feature (conflict-free LDS atomics).
__global__ __launch_bounds__(256) void pool_kernel(const float* __restrict__ acc2, const float* __restrict__ b2,
                                                   const int* __restrict__ gid, float* __restrict__ gpool,
                                                   float* __restrict__ gcnt) {
  __shared__ float lp[N_GRAPHS * HID];
  __shared__ float lc[N_GRAPHS];
  int t = threadIdx.x;
  for (int i = t; i < N_GRAPHS * HID; i += 256) lp[i] = 0.f;
  if (t < N_GRAPHS) lc[t] = 0.f;
  __syncthreads();
  int j = t & (HID - 1);
  int grp = t >> 5;  // 8 node-groups per block
  float sb = 0.f;
#pragma unroll
  for (int q = 0; q < N_REL; q++) sb += b2[q * HID + j];
  for (int n = blockIdx.x * 8 + grp; n < N_NODES; n += gridDim.x * 8) {
    int g = gid[n];
    float v = acc2[(size_t)n * HID + j] + sb;
    atomicAdd(&lp[g * HID + j], v);
    if (j == 0) atomicAdd(&lc[g], 1.f);
  }
  __syncthreads();
  for (int i = t; i < N_GRAPHS * HID; i += 256) atomicAdd(&gpool[i], lp[i]);
  if (t < N_GRAPHS) atomicAdd(&gcnt[t], lc[t]);
}

__global__ void final_kernel(const float* __restrict__ gpool, const float* __restrict__ gcnt,
                             const float* __restrict__ Wc, const float* __restrict__ bc,
                             float* __restrict__ out) {
  int g = threadIdx.x;
  if (g >= N_GRAPHS) return;
  float inv = 1.f / fmaxf(gcnt[g], 1.f);
  float o0 = bc[0], o1 = bc[1];
#pragma unroll
  for (int k = 0; k < HID; k++) {
    float p = gpool[g * HID + k] * inv;
    o0 += p * Wc[k * 2 + 0];
    o1 += p * Wc[k * 2 + 1];
  }
  out[g * 2 + 0] = o0;
  out[g * 2 + 1] = o1;
}

extern "C" void kernel_launch(void* const* d_in, const int* in_sizes, int n_in,
                              void* d_out, int out_size, void* d_ws, size_t ws_size,
                              hipStream_t stream) {
  const float* x  = (const float*)d_in[0];
  const int* src  = (const int*)d_in[1];
  const int* dst  = (const int*)d_in[2];
  const int* gid  = (const int*)d_in[3];
  const float* W1 = (const float*)d_in[5];
  const float* b1 = (const float*)d_in[6];
  const float* W2 = (const float*)d_in[7];
  const float* b2 = (const float*)d_in[8];
  const float* Wc = (const float*)d_in[9];
  const float* bc = (const float*)d_in[10];
  float* out = (float*)d_out;

  float* ws = (float*)d_ws;
  const size_t NF = (size_t)N_NODES * HID;           // 3.2M floats per node-state buffer
  const size_t RN = (size_t)N_REL * N_NODES;         // 800k
  const size_t POOLF = N_GRAPHS * HID + N_GRAPHS;    // 2112
  float* acc1  = ws;
  float* acc2  = acc1 + NF;
  float* gpool = acc2 + NF;
  float* gcnt  = gpool + N_GRAPHS * HID;
  float* rsb   = ws + (2 * NF + POOLF);              // degree/rsqrt region
  size_t wsf = ws_size / 4;
  size_t zf = 2 * NF + POOLF;                        // must be zeroed every call

  int tiles_full = (N_NODES + TILE - 1) / TILE;

  if (wsf >= zf + 2 * RN + NF) {
    // ---- Tier 1/2: all-relation degree arrays, K relations of hw at a time ----
    float* rs_o_all = rsb;            // [R][N]
    float* rs_i_all = rsb + RN;       // [R][N]
    float* hw = rsb + 2 * RN;
    size_t avail = wsf - (zf + 2 * RN);
    int K = (int)(avail / NF); if (K > N_REL) K = N_REL;

    size_t zb = (zf + 2 * RN) * 4; if (zb > ws_size) zb = ws_size;
    hipMemsetAsync(d_ws, 0, zb, stream);
    deg_kernel<<<(N_REL * N_EDGES + 255) / 256, 256, 0, stream>>>(src, dst, (int*)rs_o_all, (int*)rs_i_all, N_REL);
    rsqrt_kernel<<<(int)((2 * RN + 255) / 256), 256, 0, stream>>>(rs_o_all, (int)(2 * RN));

    for (int r0 = 0; r0 < N_REL; r0 += K) {
      int nr = (N_REL - r0 < K) ? (N_REL - r0) : K;
      proj1_kernel<<<dim3(tiles_full, nr), 256, 0, stream>>>(x, W1 + (size_t)r0 * IN_F * HID,
                                                             rs_o_all + (size_t)r0 * N_NODES, hw, 0, N_NODES, N_NODES);
      long tot = (long)nr * N_EDGES * HID;
      scatter_kernel<<<(int)((tot + 255) / 256), 256, 0, stream>>>(hw, src + (size_t)r0 * N_EDGES,
                                                                   dst + (size_t)r0 * N_EDGES,
                                                                   rs_i_all + (size_t)r0 * N_NODES,
                                                                   acc1, nr, 0, N_NODES, N_NODES);
    }
    for (int r0 = 0; r0 < N_REL; r0 += K) {
      int nr = (N_REL - r0 < K) ? (N_REL - r0) : K;
      proj2_kernel<<<dim3(tiles_full, nr), 256, 0, stream>>>(acc1, b1, W2 + (size_t)r0 * HID * HID,
                                                             rs_o_all + (size_t)r0 * N_NODES, hw, 0, N_NODES, N_NODES);
      long tot = (long)nr * N_EDGES * HID;
      scatter_kernel<<<(int)((tot + 255) / 256), 256, 0, stream>>>(hw, src + (size_t)r0 * N_EDGES,
                                                                   dst + (size_t)r0 * N_EDGES,
                                                                   rs_i_all + (size_t)r0 * N_NODES,
                                                                   acc2, nr, 0, N_NODES, N_NODES);
    }
  } else {
    // ---- Tier 3: per-relation degrees (recomputed), node-chunked hw ----
    float* rs_o = rsb;                // [N]
    float* rs_i = rsb + N_NODES;      // [N]
    float* hw = rsb + 2 * N_NODES;
    size_t fixed3 = zf + 2 * N_NODES;
    size_t avail = (wsf > fixed3) ? (wsf - fixed3) : 0;
    long chunk = (long)(avail / HID) & ~255L;
    if (chunk < 256) chunk = 256;
    if (chunk > N_NODES) chunk = N_NODES;

    size_t zb = zf * 4; if (zb > ws_size) zb = ws_size;
    hipMemsetAsync(d_ws, 0, zb, stream);

    for (int layer = 0; layer < 2; layer++) {
      for (int r = 0; r < N_REL; r++) {
        hipMemsetAsync(rs_o, 0, 2 * N_NODES * 4, stream);
        deg_kernel<<<(N_EDGES + 255) / 256, 256, 0, stream>>>(src + (size_t)r * N_EDGES, dst + (size_t)r * N_EDGES,
                                                              (int*)rs_o, (int*)rs_i, 1);
        rsqrt_kernel<<<(2 * N_NODES + 255) / 256, 256, 0, stream>>>(rs_o, 2 * N_NODES);
        for (long n0 = 0; n0 < N_NODES; n0 += chunk) {
          long n1 = n0 + chunk; if (n1 > N_NODES) n1 = N_NODES;
          int tiles = (int)((n1 - n0 + TILE - 1) / TILE);
          if (layer == 0)
            proj1_kernel<<<dim3(tiles, 1), 256, 0, stream>>>(x, W1 + (size_t)r * IN_F * HID, rs_o, hw,
                                                             (int)n0, (int)n1, (int)chunk);
          else
            proj2_kernel<<<dim3(tiles, 1), 256, 0, stream>>>(acc1, b1, W2 + (size_t)r * HID * HID, rs_o, hw,
                                                             (int)n0, (int)n1, (int)chunk);
          long tot = (long)N_EDGES * HID;
          scatter_kernel<<<(int)((tot + 255) / 256), 256, 0, stream>>>(hw, src + (size_t)r * N_EDGES,
                                                                       dst + (size_t)r * N_EDGES, rs_i,
                                                                       layer == 0 ? acc1 : acc2,
                                                                       1, (int)n0, (int)n1, (int)chunk);
        }
      }
    }
  }

  pool_kernel<<<256, 256, 0, stream>>>(acc2, b2, gid, gpool, gcnt);
  final_kernel<<<1, 64, 0, stream>>>(gpool, gcnt, Wc, bc, out);
}